// Round 1
// baseline (606.003 us; speedup 1.0000x reference)
//
#include <hip/hip_runtime.h>

// ---------------------------------------------------------------------------
// ResBlock GNN layer on MI355X (gfx950). ALL tensors fp32.
//   h  = gelu(x @ W_ff1 + b)
//   h += seg_sum(gelu(P[src]+Q[dst]+R_e+b_mp)), P=h@Wa, Q=h@Wb, R=ef@Wc  (x2)
//   out = x + h @ W_ff2 + b
// R8: FUSED edge kernel. R tile (64 edges x 256) computed by MFMA into LDS
// only -- never materialized in HBM (kills the 164MB x2 write+read round
// trip that rgemm/node did). Phase 2: thread-per-channel walks the block's
// 64 sorted edges; P-row reads wave-uniform (L2-resident Pbuf); interior dst
// segments plain-RMW Hacc, block-boundary segments atomicAdd. finalize_h
// emits h_bf for the next PQ-GEMM; FFN2 consumes Hacc directly (a_is_f32).
// ---------------------------------------------------------------------------

typedef __attribute__((ext_vector_type(8))) short short8;
typedef __attribute__((ext_vector_type(4))) float f32x4;

#define HD __device__ __forceinline__

HD unsigned short f2bf(float f) {
    unsigned int u = __float_as_uint(f);
    return (unsigned short)((u + 0x7fffu + ((u >> 16) & 1u)) >> 16);  // RNE
}
HD float bf2f(unsigned short u) { return __uint_as_float(((unsigned int)u) << 16); }

// gelu tanh-approx via sigmoid identity: 0.5(1+tanh(z)) == sigmoid(2z).
HD float gelu_f(float x) {
    float u = x * (-1.5957691216057308f - 0.07135481627f * (x * x));
    return x * __builtin_amdgcn_rcpf(1.f + __expf(u));
}

// ---------------------------------------------------------------------------
// All 8 weight repacks in one dispatch.
// ---------------------------------------------------------------------------
__global__ void repack_all(const float* __restrict__ Wff1,
                           const float* __restrict__ Wmp1,
                           const float* __restrict__ Wmp2,
                           const float* __restrict__ Wff2,
                           unsigned short* __restrict__ Bp) {
    const int begs[9] = {0, 65536, 131072, 196608, 212992, 278528, 344064,
                         360448, 425984};
    const int srcid[8] = {0, 1, 1, 1, 2, 2, 2, 3};
    const int rowoff[8] = {0, 0, 256, 512, 0, 256, 512, 0};
    int i = blockIdx.x * 256 + threadIdx.x;
    if (i >= 425984) return;
    int s = 0;
#pragma unroll
    for (int k = 1; k < 8; ++k)
        if (i >= begs[k]) s = k;
    const float* Ws[4] = {Wff1, Wmp1, Wmp2, Wff2};
    const float* B = Ws[srcid[s]];
    int local = i - begs[s];
    int k = local >> 8, n = local & 255;
    int kb = k >> 5, kr = k & 31;
    int quad = kr >> 3, j = kr & 7;
    int lane = quad * 16 + (n & 15);
    int nt = n >> 4;
    Bp[begs[s] + ((((kb * 16 + nt) * 64) + lane) << 3) + j] =
        f2bf(B[(size_t)(rowoff[s] + k) * 256 + n]);
}

// ---------------------------------------------------------------------------
// General LDS-free bf16 MFMA GEMM (64x64 tile, grid (ceil(M/64),4)) for FFNs.
// ---------------------------------------------------------------------------
__global__ __launch_bounds__(256) void gemm_kernel(
    const void* __restrict__ Av, int a_is_f32, int M, int K,
    const unsigned short* __restrict__ Bp,
    const float* __restrict__ bias, const float* __restrict__ resid,
    unsigned short* __restrict__ Cb, float* __restrict__ Cf, int do_gelu) {
    int lane = threadIdx.x & 63;
    int w = threadIdx.x >> 6;
    int row0 = blockIdx.x * 64 + w * 16;
    int n0 = blockIdx.y * 64;
    int m15 = lane & 15, quad = lane >> 4;

    int arow = row0 + m15;
    if (arow > M - 1) arow = M - 1;

    f32x4 acc[4] = {{0,0,0,0},{0,0,0,0},{0,0,0,0},{0,0,0,0}};
    const float* Af = (const float*)Av + (size_t)arow * K + quad * 8;
    const unsigned short* Ab = (const unsigned short*)Av + (size_t)arow * K + quad * 8;

    for (int kt = 0; kt < K; kt += 32) {
        short8 a;
        if (a_is_f32) {
            f32x4 lo = *(const f32x4*)(Af + kt);
            f32x4 hi = *(const f32x4*)(Af + kt + 4);
#pragma unroll
            for (int j = 0; j < 4; ++j) {
                a[j] = (short)f2bf(lo[j]);
                a[j + 4] = (short)f2bf(hi[j]);
            }
        } else {
            a = *(const short8*)(Ab + kt);
        }
        const unsigned short* bbase =
            Bp + ((((size_t)(kt >> 5) * 16 + (n0 >> 4)) * 64 + lane) << 3);
#pragma unroll
        for (int nt = 0; nt < 4; ++nt) {
            short8 b = *(const short8*)(bbase + nt * 64 * 8);
            acc[nt] = __builtin_amdgcn_mfma_f32_16x16x32_bf16(a, b, acc[nt], 0, 0, 0);
        }
    }

#pragma unroll
    for (int nt = 0; nt < 4; ++nt) {
        int col = n0 + nt * 16 + m15;
        float bv = bias ? bias[col] : 0.f;
#pragma unroll
        for (int r = 0; r < 4; ++r) {
            int row = row0 + quad * 4 + r;
            if (row < M) {
                float v = acc[nt][r] + bv;
                if (do_gelu) v = gelu_f(v);
                size_t idx = (size_t)row * 256 + col;
                if (resid) v += resid[idx];
                if (Cb) Cb[idx] = f2bf(v);
                if (Cf) Cf[idx] = v;
            }
        }
    }
}

// ---------------------------------------------------------------------------
// P and Q in one dispatch: grid ((M+63)/64, 8); y<4 -> P cols, y>=4 -> Q cols.
// ---------------------------------------------------------------------------
__global__ __launch_bounds__(256) void pq_kernel(
    const unsigned short* __restrict__ A, int M,
    const unsigned short* __restrict__ BpA, const unsigned short* __restrict__ BpB,
    const float* __restrict__ qbias,
    unsigned short* __restrict__ Pb, unsigned short* __restrict__ Qb) {
    int lane = threadIdx.x & 63;
    int w = threadIdx.x >> 6;
    int row0 = blockIdx.x * 64 + w * 16;
    int isQ = blockIdx.y >> 2;
    int n0 = (blockIdx.y & 3) * 64;
    const unsigned short* Bp = isQ ? BpB : BpA;
    unsigned short* out = isQ ? Qb : Pb;
    int m15 = lane & 15, quad = lane >> 4;

    int arow = row0 + m15;
    if (arow > M - 1) arow = M - 1;
    const unsigned short* Ab = A + (size_t)arow * 256 + quad * 8;

    f32x4 acc[4] = {{0,0,0,0},{0,0,0,0},{0,0,0,0},{0,0,0,0}};
    for (int kt = 0; kt < 256; kt += 32) {
        short8 a = *(const short8*)(Ab + kt);
        const unsigned short* bbase =
            Bp + ((((size_t)(kt >> 5) * 16 + (n0 >> 4)) * 64 + lane) << 3);
#pragma unroll
        for (int nt = 0; nt < 4; ++nt) {
            short8 b = *(const short8*)(bbase + nt * 64 * 8);
            acc[nt] = __builtin_amdgcn_mfma_f32_16x16x32_bf16(a, b, acc[nt], 0, 0, 0);
        }
    }

#pragma unroll
    for (int nt = 0; nt < 4; ++nt) {
        int col = n0 + nt * 16 + m15;
        float bv = isQ ? qbias[col] : 0.f;
#pragma unroll
        for (int r = 0; r < 4; ++r) {
            int row = row0 + quad * 4 + r;
            if (row < M) out[(size_t)row * 256 + col] = f2bf(acc[nt][r] + bv);
        }
    }
}

// ---------------------------------------------------------------------------
// Counting sort by dst: zero -> histogram -> single-block scan -> scatter.
// ---------------------------------------------------------------------------
__global__ void zero_i32(int* __restrict__ p, int n) {
    int i = blockIdx.x * 256 + threadIdx.x;
    if (i < n) p[i] = 0;
}
__global__ void hist_kernel(const int* __restrict__ dst, int* __restrict__ cnt, int E) {
    int e = blockIdx.x * 256 + threadIdx.x;
    if (e < E) atomicAdd(&cnt[dst[e]], 1);
}
__global__ __launch_bounds__(1024) void scan_kernel(const int* __restrict__ cnt,
                                                    int* __restrict__ cursor, int N) {
    __shared__ int part[1024];
    int tid = threadIdx.x;
    int per = (N + 1023) / 1024;
    int lo = tid * per;
    int s = 0;
    for (int j = 0; j < per; ++j) {
        int idx = lo + j;
        if (idx < N) s += cnt[idx];
    }
    part[tid] = s;
    __syncthreads();
    for (int off = 1; off < 1024; off <<= 1) {
        int t = (tid >= off) ? part[tid - off] : 0;
        __syncthreads();
        part[tid] += t;
        __syncthreads();
    }
    int run = (tid > 0) ? part[tid - 1] : 0;
    for (int j = 0; j < per; ++j) {
        int idx = lo + j;
        if (idx < N) {
            cursor[idx] = run;
            run += cnt[idx];
        }
    }
}
__global__ void scatter_kernel(const int* __restrict__ src, const int* __restrict__ dst,
                               int* __restrict__ cursor, int* __restrict__ perm,
                               int* __restrict__ srcs, int* __restrict__ dsts, int E) {
    int e = blockIdx.x * 256 + threadIdx.x;
    if (e < E) {
        int d = dst[e];
        int pos = atomicAdd(&cursor[d], 1);
        perm[pos] = e;
        srcs[pos] = src[e];
        dsts[pos] = d;
    }
}

// ---------------------------------------------------------------------------
// FUSED edge kernel. Block = 64 sorted edges (grid ceil(E/64), 256 thr).
// Phase 1 (rgemm body): R[64x256] = bf16(ef[perm[e]] @ Wc) -> LDS tile.
// Phase 2: thread-per-channel (c = threadIdx.x); walk dst segments of the
// block's edges; acc += gelu(P[src][c] + Q[d][c] + R_lds[e][c]); interior
// segments plain-RMW Hacc[d][c], boundary segments atomicAdd.
// ---------------------------------------------------------------------------
__global__ __launch_bounds__(256) void fused_kernel(
    const float* __restrict__ ef, const int* __restrict__ perm,
    const int* __restrict__ srcs, const int* __restrict__ dsts,
    const unsigned short* __restrict__ BpC,
    const unsigned short* __restrict__ Pb, const unsigned short* __restrict__ Qb,
    const int* __restrict__ cursor, const int* __restrict__ cnt,
    float* __restrict__ Hacc, int E) {
    __shared__ unsigned short tile[64 * 256];  // 32 KB, R tile bf16
    int lane = threadIdx.x & 63;
    int w = threadIdx.x >> 6;
    int e_lo = blockIdx.x * 64;
    int e_hi = e_lo + 64;
    if (e_hi > E) e_hi = E;

    // per-lane src/dst of the block's 64 edges (broadcast via readlane later)
    int eidx = e_lo + lane;
    if (eidx > E - 1) eidx = E - 1;
    int vs = srcs[eidx];
    int vd = dsts[eidx];

    // ---- Phase 1: MFMA R tile (identical math to old rgemm_kernel) ----
    int m15 = lane & 15, quad = lane >> 4;
    int arow = e_lo + w * 16 + m15;
    if (arow > E - 1) arow = E - 1;
    int grow = perm[arow];
    const float* Af = ef + (size_t)grow * 64 + quad * 8;

    f32x4 acc[16];
#pragma unroll
    for (int i = 0; i < 16; ++i) acc[i] = {0.f, 0.f, 0.f, 0.f};

#pragma unroll
    for (int kb = 0; kb < 2; ++kb) {
        f32x4 lo = *(const f32x4*)(Af + kb * 32);
        f32x4 hi = *(const f32x4*)(Af + kb * 32 + 4);
        short8 a;
#pragma unroll
        for (int j = 0; j < 4; ++j) {
            a[j] = (short)f2bf(lo[j]);
            a[j + 4] = (short)f2bf(hi[j]);
        }
        const unsigned short* bb = BpC + (((size_t)kb * 16 * 64 + lane) << 3);
#pragma unroll
        for (int nt = 0; nt < 16; ++nt) {
            short8 b = *(const short8*)(bb + (size_t)nt * 64 * 8);
            acc[nt] = __builtin_amdgcn_mfma_f32_16x16x32_bf16(a, b, acc[nt], 0, 0, 0);
        }
    }

#pragma unroll
    for (int nt = 0; nt < 16; ++nt) {
        int col = nt * 16 + m15;
#pragma unroll
        for (int r = 0; r < 4; ++r) {
            int lrow = w * 16 + quad * 4 + r;
            tile[lrow * 256 + col] = f2bf(acc[nt][r]);
        }
    }
    __syncthreads();

    // ---- Phase 2: segmented aggregation, one channel per thread ----
    int c = threadIdx.x;
    int i = e_lo;
    while (i < e_hi) {
        int d = __builtin_amdgcn_readlane(vd, i - e_lo);  // wave-uniform
        int end = cursor[d];
        int beg = end - cnt[d];
        int seg_end = end < e_hi ? end : e_hi;
        float qv = bf2f(Qb[(((size_t)d) << 8) + c]);
        float a = 0.f;
        for (; i < seg_end; ++i) {
            int s = __builtin_amdgcn_readlane(vs, i - e_lo);  // wave-uniform
            float pv = bf2f(Pb[(((size_t)s) << 8) + c]);
            float rv = bf2f(tile[((i - e_lo) << 8) + c]);
            a += gelu_f(pv + qv + rv);
        }
        size_t hidx = (((size_t)d) << 8) + c;
        if (beg >= e_lo && end <= e_hi)
            Hacc[hidx] += a;              // whole segment owned by this block
        else
            atomicAdd(&Hacc[hidx], a);    // segment cut by block boundary
    }
}

// ---------------------------------------------------------------------------
// h_bf = bf16(Hacc), vectorized (float4 -> uint2). n4 = N*256/4.
// ---------------------------------------------------------------------------
__global__ void finalize_h(const float* __restrict__ Hacc,
                           unsigned short* __restrict__ h_bf, int n4) {
    int i = blockIdx.x * 256 + threadIdx.x;
    if (i < n4) {
        float4 v = ((const float4*)Hacc)[i];
        uint2 o;
        o.x = (unsigned int)f2bf(v.x) | ((unsigned int)f2bf(v.y) << 16);
        o.y = (unsigned int)f2bf(v.z) | ((unsigned int)f2bf(v.w) << 16);
        ((uint2*)h_bf)[i] = o;
    }
}

// ---------------------------------------------------------------------------
extern "C" void kernel_launch(void* const* d_in, const int* in_sizes, int n_in,
                              void* d_out, int out_size, void* d_ws, size_t ws_size,
                              hipStream_t stream) {
    const float* x     = (const float*)d_in[0];
    const int*   ei    = (const int*)d_in[1];
    const float* ef    = (const float*)d_in[2];
    const float* W_ff1 = (const float*)d_in[3];
    const float* b_ff1 = (const float*)d_in[4];
    const float* W_mp1 = (const float*)d_in[5];
    const float* b_mp1 = (const float*)d_in[6];
    const float* W_mp2 = (const float*)d_in[7];
    const float* b_mp2 = (const float*)d_in[8];
    const float* W_ff2 = (const float*)d_in[9];
    const float* b_ff2 = (const float*)d_in[10];

    const int N = in_sizes[0] / 256;  // 10000
    const int E = in_sizes[1] / 2;    // 320000
    const int* src = ei;
    const int* dst = ei + E;

    // ---- workspace carve (256B-aligned bumps) ----
    char* p = (char*)d_ws;
    unsigned short* h_bf = (unsigned short*)p;  p += ((size_t)N * 256 * 2 + 255) & ~255ull;
    unsigned short* Pbuf = (unsigned short*)p;  p += ((size_t)N * 256 * 2 + 255) & ~255ull;
    unsigned short* Qbuf = (unsigned short*)p;  p += ((size_t)N * 256 * 2 + 255) & ~255ull;
    float* Hacc = (float*)p;                    p += ((size_t)N * 256 * 4 + 255) & ~255ull;
    unsigned short* Bp = (unsigned short*)p;    p += (425984ull * 2 + 255) & ~255ull;
    int* cnt    = (int*)p;                      p += ((size_t)N * 4 + 255) & ~255ull;
    int* cursor = (int*)p;                      p += ((size_t)N * 4 + 255) & ~255ull;
    int* perm   = (int*)p;                      p += ((size_t)E * 4 + 255) & ~255ull;
    int* srcs   = (int*)p;                      p += ((size_t)E * 4 + 255) & ~255ull;
    int* dsts   = (int*)p;                      p += ((size_t)E * 4 + 255) & ~255ull;

    unsigned short* Bp_ff1 = Bp + 0;
    unsigned short* Bp_a1  = Bp + 65536;
    unsigned short* Bp_b1  = Bp + 131072;
    unsigned short* Bp_c1  = Bp + 196608;
    unsigned short* Bp_a2  = Bp + 212992;
    unsigned short* Bp_b2  = Bp + 278528;
    unsigned short* Bp_c2  = Bp + 344064;
    unsigned short* Bp_ff2 = Bp + 360448;

    // ---- repack all weights (single dispatch) ----
    repack_all<<<1664, 256, 0, stream>>>(W_ff1, W_mp1, W_mp2, W_ff2, Bp);

    // ---- counting sort of edges by dst (CSR) ----
    zero_i32<<<(N + 255) / 256, 256, 0, stream>>>(cnt, N);
    hist_kernel<<<(E + 255) / 256, 256, 0, stream>>>(dst, cnt, E);
    scan_kernel<<<1, 1024, 0, stream>>>(cnt, cursor, N);
    scatter_kernel<<<(E + 255) / 256, 256, 0, stream>>>(src, dst, cursor, perm, srcs,
                                                        dsts, E);

    dim3 gN((N + 63) / 64, 4);
    dim3 gPQ((N + 63) / 64, 8);

    // ---- FFN1: h = gelu(x@W_ff1 + b); h_bf for GEMMs, Hacc = f32 accumulator
    gemm_kernel<<<gN, 256, 0, stream>>>(x, 1, N, 256, Bp_ff1, b_ff1, nullptr,
                                        h_bf, Hacc, 1);

    const unsigned short* Bp_a[2] = {Bp_a1, Bp_a2};
    const unsigned short* Bp_b[2] = {Bp_b1, Bp_b2};
    const unsigned short* Bp_c[2] = {Bp_c1, Bp_c2};
    const float* bmp[2] = {b_mp1, b_mp2};

    for (int l = 0; l < 2; ++l) {
        pq_kernel<<<gPQ, 256, 0, stream>>>(h_bf, N, Bp_a[l], Bp_b[l], bmp[l],
                                           Pbuf, Qbuf);
        fused_kernel<<<(E + 63) / 64, 256, 0, stream>>>(
            ef, perm, srcs, dsts, Bp_c[l], Pbuf, Qbuf, cursor, cnt, Hacc, E);
        if (l == 0)
            finalize_h<<<(N * 64 + 255) / 256, 256, 0, stream>>>(Hacc, h_bf, N * 64);
    }

    // ---- FFN2: out = x + bf16(Hacc)@W_ff2 + b  (reads Hacc directly) ----
    gemm_kernel<<<gN, 256, 0, stream>>>(Hacc, 1, N, 256, Bp_ff2, b_ff2, x,
                                        nullptr, (float*)d_out, 0);
}

// Round 2
// 574.093 us; speedup vs baseline: 1.0556x; 1.0556x over previous
//
#include <hip/hip_runtime.h>

// ---------------------------------------------------------------------------
// ResBlock GNN layer on MI355X (gfx950). ALL tensors fp32.
//   h  = gelu(x @ W_ff1 + b)
//   h += seg_sum(gelu(P[src]+Q[dst]+R_e+b_mp)), P=h@Wa, Q=h@Wb, R=ef@Wc  (x2)
//   out = x + h @ W_ff2 + b
// R9: fused edge kernel, latency-batched phase 2. Wave w consumes exactly the
// 16 R-rows it produced in phase 1 (LDS tile, wave-local). 4 channels/thread
// (uint2), P/R preloaded in chunks of 8 independent loads (old node_kernel's
// proven pipeline), segment flushes are fire-and-forget atomicAdd to Hacc.
// No cursor/cnt reads in the hot loop. R never touches HBM.
// ---------------------------------------------------------------------------

typedef __attribute__((ext_vector_type(8))) short short8;
typedef __attribute__((ext_vector_type(4))) float f32x4;

#define HD __device__ __forceinline__

HD unsigned short f2bf(float f) {
    unsigned int u = __float_as_uint(f);
    return (unsigned short)((u + 0x7fffu + ((u >> 16) & 1u)) >> 16);  // RNE
}
HD float lo16(unsigned int u) { return __uint_as_float(u << 16); }
HD float hi16(unsigned int u) { return __uint_as_float(u & 0xffff0000u); }
HD float bf2f(unsigned short u) { return __uint_as_float(((unsigned int)u) << 16); }

// gelu tanh-approx via sigmoid identity: 0.5(1+tanh(z)) == sigmoid(2z).
HD float gelu_f(float x) {
    float u = x * (-1.5957691216057308f - 0.07135481627f * (x * x));
    return x * __builtin_amdgcn_rcpf(1.f + __expf(u));
}

// ---------------------------------------------------------------------------
// All 8 weight repacks in one dispatch.
// ---------------------------------------------------------------------------
__global__ void repack_all(const float* __restrict__ Wff1,
                           const float* __restrict__ Wmp1,
                           const float* __restrict__ Wmp2,
                           const float* __restrict__ Wff2,
                           unsigned short* __restrict__ Bp) {
    const int begs[9] = {0, 65536, 131072, 196608, 212992, 278528, 344064,
                         360448, 425984};
    const int srcid[8] = {0, 1, 1, 1, 2, 2, 2, 3};
    const int rowoff[8] = {0, 0, 256, 512, 0, 256, 512, 0};
    int i = blockIdx.x * 256 + threadIdx.x;
    if (i >= 425984) return;
    int s = 0;
#pragma unroll
    for (int k = 1; k < 8; ++k)
        if (i >= begs[k]) s = k;
    const float* Ws[4] = {Wff1, Wmp1, Wmp2, Wff2};
    const float* B = Ws[srcid[s]];
    int local = i - begs[s];
    int k = local >> 8, n = local & 255;
    int kb = k >> 5, kr = k & 31;
    int quad = kr >> 3, j = kr & 7;
    int lane = quad * 16 + (n & 15);
    int nt = n >> 4;
    Bp[begs[s] + ((((kb * 16 + nt) * 64) + lane) << 3) + j] =
        f2bf(B[(size_t)(rowoff[s] + k) * 256 + n]);
}

// ---------------------------------------------------------------------------
// General LDS-free bf16 MFMA GEMM (64x64 tile, grid (ceil(M/64),4)) for FFNs.
// ---------------------------------------------------------------------------
__global__ __launch_bounds__(256) void gemm_kernel(
    const void* __restrict__ Av, int a_is_f32, int M, int K,
    const unsigned short* __restrict__ Bp,
    const float* __restrict__ bias, const float* __restrict__ resid,
    unsigned short* __restrict__ Cb, float* __restrict__ Cf, int do_gelu) {
    int lane = threadIdx.x & 63;
    int w = threadIdx.x >> 6;
    int row0 = blockIdx.x * 64 + w * 16;
    int n0 = blockIdx.y * 64;
    int m15 = lane & 15, quad = lane >> 4;

    int arow = row0 + m15;
    if (arow > M - 1) arow = M - 1;

    f32x4 acc[4] = {{0,0,0,0},{0,0,0,0},{0,0,0,0},{0,0,0,0}};
    const float* Af = (const float*)Av + (size_t)arow * K + quad * 8;
    const unsigned short* Ab = (const unsigned short*)Av + (size_t)arow * K + quad * 8;

    for (int kt = 0; kt < K; kt += 32) {
        short8 a;
        if (a_is_f32) {
            f32x4 lo = *(const f32x4*)(Af + kt);
            f32x4 hi = *(const f32x4*)(Af + kt + 4);
#pragma unroll
            for (int j = 0; j < 4; ++j) {
                a[j] = (short)f2bf(lo[j]);
                a[j + 4] = (short)f2bf(hi[j]);
            }
        } else {
            a = *(const short8*)(Ab + kt);
        }
        const unsigned short* bbase =
            Bp + ((((size_t)(kt >> 5) * 16 + (n0 >> 4)) * 64 + lane) << 3);
#pragma unroll
        for (int nt = 0; nt < 4; ++nt) {
            short8 b = *(const short8*)(bbase + nt * 64 * 8);
            acc[nt] = __builtin_amdgcn_mfma_f32_16x16x32_bf16(a, b, acc[nt], 0, 0, 0);
        }
    }

#pragma unroll
    for (int nt = 0; nt < 4; ++nt) {
        int col = n0 + nt * 16 + m15;
        float bv = bias ? bias[col] : 0.f;
#pragma unroll
        for (int r = 0; r < 4; ++r) {
            int row = row0 + quad * 4 + r;
            if (row < M) {
                float v = acc[nt][r] + bv;
                if (do_gelu) v = gelu_f(v);
                size_t idx = (size_t)row * 256 + col;
                if (resid) v += resid[idx];
                if (Cb) Cb[idx] = f2bf(v);
                if (Cf) Cf[idx] = v;
            }
        }
    }
}

// ---------------------------------------------------------------------------
// P and Q in one dispatch: grid ((M+63)/64, 8); y<4 -> P cols, y>=4 -> Q cols.
// ---------------------------------------------------------------------------
__global__ __launch_bounds__(256) void pq_kernel(
    const unsigned short* __restrict__ A, int M,
    const unsigned short* __restrict__ BpA, const unsigned short* __restrict__ BpB,
    const float* __restrict__ qbias,
    unsigned short* __restrict__ Pb, unsigned short* __restrict__ Qb) {
    int lane = threadIdx.x & 63;
    int w = threadIdx.x >> 6;
    int row0 = blockIdx.x * 64 + w * 16;
    int isQ = blockIdx.y >> 2;
    int n0 = (blockIdx.y & 3) * 64;
    const unsigned short* Bp = isQ ? BpB : BpA;
    unsigned short* out = isQ ? Qb : Pb;
    int m15 = lane & 15, quad = lane >> 4;

    int arow = row0 + m15;
    if (arow > M - 1) arow = M - 1;
    const unsigned short* Ab = A + (size_t)arow * 256 + quad * 8;

    f32x4 acc[4] = {{0,0,0,0},{0,0,0,0},{0,0,0,0},{0,0,0,0}};
    for (int kt = 0; kt < 256; kt += 32) {
        short8 a = *(const short8*)(Ab + kt);
        const unsigned short* bbase =
            Bp + ((((size_t)(kt >> 5) * 16 + (n0 >> 4)) * 64 + lane) << 3);
#pragma unroll
        for (int nt = 0; nt < 4; ++nt) {
            short8 b = *(const short8*)(bbase + nt * 64 * 8);
            acc[nt] = __builtin_amdgcn_mfma_f32_16x16x32_bf16(a, b, acc[nt], 0, 0, 0);
        }
    }

#pragma unroll
    for (int nt = 0; nt < 4; ++nt) {
        int col = n0 + nt * 16 + m15;
        float bv = isQ ? qbias[col] : 0.f;
#pragma unroll
        for (int r = 0; r < 4; ++r) {
            int row = row0 + quad * 4 + r;
            if (row < M) out[(size_t)row * 256 + col] = f2bf(acc[nt][r] + bv);
        }
    }
}

// ---------------------------------------------------------------------------
// Counting sort by dst: zero -> histogram -> single-block scan -> scatter.
// ---------------------------------------------------------------------------
__global__ void zero_i32(int* __restrict__ p, int n) {
    int i = blockIdx.x * 256 + threadIdx.x;
    if (i < n) p[i] = 0;
}
__global__ void hist_kernel(const int* __restrict__ dst, int* __restrict__ cnt, int E) {
    int e = blockIdx.x * 256 + threadIdx.x;
    if (e < E) atomicAdd(&cnt[dst[e]], 1);
}
__global__ __launch_bounds__(1024) void scan_kernel(const int* __restrict__ cnt,
                                                    int* __restrict__ cursor, int N) {
    __shared__ int part[1024];
    int tid = threadIdx.x;
    int per = (N + 1023) / 1024;
    int lo = tid * per;
    int s = 0;
    for (int j = 0; j < per; ++j) {
        int idx = lo + j;
        if (idx < N) s += cnt[idx];
    }
    part[tid] = s;
    __syncthreads();
    for (int off = 1; off < 1024; off <<= 1) {
        int t = (tid >= off) ? part[tid - off] : 0;
        __syncthreads();
        part[tid] += t;
        __syncthreads();
    }
    int run = (tid > 0) ? part[tid - 1] : 0;
    for (int j = 0; j < per; ++j) {
        int idx = lo + j;
        if (idx < N) {
            cursor[idx] = run;
            run += cnt[idx];
        }
    }
}
__global__ void scatter_kernel(const int* __restrict__ src, const int* __restrict__ dst,
                               int* __restrict__ cursor, int* __restrict__ perm,
                               int* __restrict__ srcs, int* __restrict__ dsts, int E) {
    int e = blockIdx.x * 256 + threadIdx.x;
    if (e < E) {
        int d = dst[e];
        int pos = atomicAdd(&cursor[d], 1);
        perm[pos] = e;
        srcs[pos] = src[e];
        dsts[pos] = d;
    }
}

// ---------------------------------------------------------------------------
// FUSED edge kernel. Block = 64 sorted edges (grid ceil(E/64), 256 thr).
// Phase 1: R[64x256] = bf16(ef[perm[e]] @ Wc) -> LDS tile (MFMA).
// Phase 2: wave w owns edges [w*16, w*16+16) of the block (the exact rows it
// wrote in phase 1). 4 channels/thread (uint2). P (global gather, uniform
// src) and R (LDS) preloaded 8-at-a-time -> 8 loads in flight. Segment
// partial sums flushed with fire-and-forget atomicAdd into Hacc.
// ---------------------------------------------------------------------------
__global__ __launch_bounds__(256) void fused_kernel(
    const float* __restrict__ ef, const int* __restrict__ perm,
    const int* __restrict__ srcs, const int* __restrict__ dsts,
    const unsigned short* __restrict__ BpC,
    const unsigned short* __restrict__ Pb, const unsigned short* __restrict__ Qb,
    float* __restrict__ Hacc, int E) {
    __shared__ unsigned short tile[64 * 256];  // 32 KB, R tile bf16
    int lane = threadIdx.x & 63;
    int w = threadIdx.x >> 6;
    int e_lo = blockIdx.x * 64;
    int n_e = E - e_lo;
    if (n_e > 64) n_e = 64;

    // per-lane src/dst of the block's 64 edges (broadcast via readlane later)
    int eidx = e_lo + lane;
    if (eidx > E - 1) eidx = E - 1;
    int vs = srcs[eidx];
    int vd = dsts[eidx];

    // ---- Phase 1: MFMA R tile (identical math to old rgemm_kernel) ----
    int m15 = lane & 15, quad = lane >> 4;
    int arow = e_lo + w * 16 + m15;
    if (arow > E - 1) arow = E - 1;
    int grow = perm[arow];
    const float* Af = ef + (size_t)grow * 64 + quad * 8;

    f32x4 acc[16];
#pragma unroll
    for (int i = 0; i < 16; ++i) acc[i] = {0.f, 0.f, 0.f, 0.f};

#pragma unroll
    for (int kb = 0; kb < 2; ++kb) {
        f32x4 lo = *(const f32x4*)(Af + kb * 32);
        f32x4 hi = *(const f32x4*)(Af + kb * 32 + 4);
        short8 a;
#pragma unroll
        for (int j = 0; j < 4; ++j) {
            a[j] = (short)f2bf(lo[j]);
            a[j + 4] = (short)f2bf(hi[j]);
        }
        const unsigned short* bb = BpC + (((size_t)kb * 16 * 64 + lane) << 3);
#pragma unroll
        for (int nt = 0; nt < 16; ++nt) {
            short8 b = *(const short8*)(bb + (size_t)nt * 64 * 8);
            acc[nt] = __builtin_amdgcn_mfma_f32_16x16x32_bf16(a, b, acc[nt], 0, 0, 0);
        }
    }

#pragma unroll
    for (int nt = 0; nt < 16; ++nt) {
        int col = nt * 16 + m15;
#pragma unroll
        for (int r = 0; r < 4; ++r) {
            int lrow = w * 16 + quad * 4 + r;
            tile[lrow * 256 + col] = f2bf(acc[nt][r]);
        }
    }
    __syncthreads();

    // ---- Phase 2: wave-local 16-edge window, 4 channels/thread ----
    int base = w * 16;
    if (base < n_e) {
        int c0 = lane << 2;
        int lim = n_e - base;
        if (lim > 16) lim = 16;

        float4 a4 = {0.f, 0.f, 0.f, 0.f};
        int cur_d = __builtin_amdgcn_readlane(vd, base);
        uint2 qu = *(const uint2*)(Qb + (((size_t)cur_d) << 8) + c0);

#pragma unroll
        for (int k0 = 0; k0 < 16; k0 += 8) {
            // batch: 8 independent P gathers + 8 LDS R reads in flight
            uint2 pu[8], ru[8];
#pragma unroll
            for (int j = 0; j < 8; ++j) {
                int s = __builtin_amdgcn_readlane(vs, base + k0 + j);
                pu[j] = *(const uint2*)(Pb + (((size_t)s) << 8) + c0);
                ru[j] = *(const uint2*)(tile + ((base + k0 + j) << 8) + c0);
            }
#pragma unroll
            for (int j = 0; j < 8; ++j) {
                if (k0 + j < lim) {
                    int d = __builtin_amdgcn_readlane(vd, base + k0 + j);
                    if (d != cur_d) {
                        float* hp = Hacc + (((size_t)cur_d) << 8) + c0;
                        atomicAdd(hp + 0, a4.x);
                        atomicAdd(hp + 1, a4.y);
                        atomicAdd(hp + 2, a4.z);
                        atomicAdd(hp + 3, a4.w);
                        a4 = {0.f, 0.f, 0.f, 0.f};
                        cur_d = d;
                        qu = *(const uint2*)(Qb + (((size_t)d) << 8) + c0);
                    }
                    float q0 = lo16(qu.x), q1 = hi16(qu.x);
                    float q2 = lo16(qu.y), q3 = hi16(qu.y);
                    a4.x += gelu_f(lo16(pu[j].x) + q0 + lo16(ru[j].x));
                    a4.y += gelu_f(hi16(pu[j].x) + q1 + hi16(ru[j].x));
                    a4.z += gelu_f(lo16(pu[j].y) + q2 + lo16(ru[j].y));
                    a4.w += gelu_f(hi16(pu[j].y) + q3 + hi16(ru[j].y));
                }
            }
        }
        float* hp = Hacc + (((size_t)cur_d) << 8) + c0;
        atomicAdd(hp + 0, a4.x);
        atomicAdd(hp + 1, a4.y);
        atomicAdd(hp + 2, a4.z);
        atomicAdd(hp + 3, a4.w);
    }
}

// ---------------------------------------------------------------------------
// h_bf = bf16(Hacc), vectorized (float4 -> uint2). n4 = N*256/4.
// ---------------------------------------------------------------------------
__global__ void finalize_h(const float* __restrict__ Hacc,
                           unsigned short* __restrict__ h_bf, int n4) {
    int i = blockIdx.x * 256 + threadIdx.x;
    if (i < n4) {
        float4 v = ((const float4*)Hacc)[i];
        uint2 o;
        o.x = (unsigned int)f2bf(v.x) | ((unsigned int)f2bf(v.y) << 16);
        o.y = (unsigned int)f2bf(v.z) | ((unsigned int)f2bf(v.w) << 16);
        ((uint2*)h_bf)[i] = o;
    }
}

// ---------------------------------------------------------------------------
extern "C" void kernel_launch(void* const* d_in, const int* in_sizes, int n_in,
                              void* d_out, int out_size, void* d_ws, size_t ws_size,
                              hipStream_t stream) {
    const float* x     = (const float*)d_in[0];
    const int*   ei    = (const int*)d_in[1];
    const float* ef    = (const float*)d_in[2];
    const float* W_ff1 = (const float*)d_in[3];
    const float* b_ff1 = (const float*)d_in[4];
    const float* W_mp1 = (const float*)d_in[5];
    const float* b_mp1 = (const float*)d_in[6];
    const float* W_mp2 = (const float*)d_in[7];
    const float* b_mp2 = (const float*)d_in[8];
    const float* W_ff2 = (const float*)d_in[9];
    const float* b_ff2 = (const float*)d_in[10];

    const int N = in_sizes[0] / 256;  // 10000
    const int E = in_sizes[1] / 2;    // 320000
    const int* src = ei;
    const int* dst = ei + E;

    // ---- workspace carve (256B-aligned bumps) ----
    char* p = (char*)d_ws;
    unsigned short* h_bf = (unsigned short*)p;  p += ((size_t)N * 256 * 2 + 255) & ~255ull;
    unsigned short* Pbuf = (unsigned short*)p;  p += ((size_t)N * 256 * 2 + 255) & ~255ull;
    unsigned short* Qbuf = (unsigned short*)p;  p += ((size_t)N * 256 * 2 + 255) & ~255ull;
    float* Hacc = (float*)p;                    p += ((size_t)N * 256 * 4 + 255) & ~255ull;
    unsigned short* Bp = (unsigned short*)p;    p += (425984ull * 2 + 255) & ~255ull;
    int* cnt    = (int*)p;                      p += ((size_t)N * 4 + 255) & ~255ull;
    int* cursor = (int*)p;                      p += ((size_t)N * 4 + 255) & ~255ull;
    int* perm   = (int*)p;                      p += ((size_t)E * 4 + 255) & ~255ull;
    int* srcs   = (int*)p;                      p += ((size_t)E * 4 + 255) & ~255ull;
    int* dsts   = (int*)p;                      p += ((size_t)E * 4 + 255) & ~255ull;

    unsigned short* Bp_ff1 = Bp + 0;
    unsigned short* Bp_a1  = Bp + 65536;
    unsigned short* Bp_b1  = Bp + 131072;
    unsigned short* Bp_c1  = Bp + 196608;
    unsigned short* Bp_a2  = Bp + 212992;
    unsigned short* Bp_b2  = Bp + 278528;
    unsigned short* Bp_c2  = Bp + 344064;
    unsigned short* Bp_ff2 = Bp + 360448;

    // ---- repack all weights (single dispatch) ----
    repack_all<<<1664, 256, 0, stream>>>(W_ff1, W_mp1, W_mp2, W_ff2, Bp);

    // ---- counting sort of edges by dst (CSR) ----
    zero_i32<<<(N + 255) / 256, 256, 0, stream>>>(cnt, N);
    hist_kernel<<<(E + 255) / 256, 256, 0, stream>>>(dst, cnt, E);
    scan_kernel<<<1, 1024, 0, stream>>>(cnt, cursor, N);
    scatter_kernel<<<(E + 255) / 256, 256, 0, stream>>>(src, dst, cursor, perm, srcs,
                                                        dsts, E);

    dim3 gN((N + 63) / 64, 4);
    dim3 gPQ((N + 63) / 64, 8);

    // ---- FFN1: h = gelu(x@W_ff1 + b); h_bf for GEMMs, Hacc = f32 accumulator
    gemm_kernel<<<gN, 256, 0, stream>>>(x, 1, N, 256, Bp_ff1, b_ff1, nullptr,
                                        h_bf, Hacc, 1);

    const unsigned short* Bp_a[2] = {Bp_a1, Bp_a2};
    const unsigned short* Bp_b[2] = {Bp_b1, Bp_b2};
    const unsigned short* Bp_c[2] = {Bp_c1, Bp_c2};
    const float* bmp[2] = {b_mp1, b_mp2};

    for (int l = 0; l < 2; ++l) {
        pq_kernel<<<gPQ, 256, 0, stream>>>(h_bf, N, Bp_a[l], Bp_b[l], bmp[l],
                                           Pbuf, Qbuf);
        fused_kernel<<<(E + 63) / 64, 256, 0, stream>>>(
            ef, perm, srcs, dsts, Bp_c[l], Pbuf, Qbuf, Hacc, E);
        if (l == 0)
            finalize_h<<<(N * 64 + 255) / 256, 256, 0, stream>>>(Hacc, h_bf, N * 64);
    }

    // ---- FFN2: out = x + bf16(Hacc)@W_ff2 + b  (reads Hacc directly) ----
    gemm_kernel<<<gN, 256, 0, stream>>>(Hacc, 1, N, 256, Bp_ff2, b_ff2, x,
                                        nullptr, (float*)d_out, 0);
}

// Round 4
// 518.258 us; speedup vs baseline: 1.1693x; 1.1077x over previous
//
#include <hip/hip_runtime.h>

// ---------------------------------------------------------------------------
// ResBlock GNN layer on MI355X (gfx950). ALL tensors fp32.
//   h  = gelu(x @ W_ff1 + b)
//   h += seg_sum(gelu(P[src]+Q[dst]+R_e+b_mp)), P=h@Wa, Q=h@Wb, R=ef@Wc  (x2)
//   out = x + h @ W_ff2 + b
// R10b: fused edge kernel, CHANNEL-SLICED phase 2 (resubmit of R10 after
// infra failure; readlane double-wrap removed). Wave w owns channels
// [w*64, w*64+64) (1 ch/lane) and walks all 64 block edges with 8-deep load
// batching (8 independent 128B P-gathers + 8 LDS R reads in flight).
// Channel-disjoint waves => interior segments (fully inside the block, one
// scalar cursor/cnt check per segment) flush with PLAIN RMW to Hacc; only
// block-boundary segments (<=2/block) use atomicAdd. R tile LDS-only (MFMA).
// ---------------------------------------------------------------------------

typedef __attribute__((ext_vector_type(8))) short short8;
typedef __attribute__((ext_vector_type(4))) float f32x4;

#define HD __device__ __forceinline__

HD unsigned short f2bf(float f) {
    unsigned int u = __float_as_uint(f);
    return (unsigned short)((u + 0x7fffu + ((u >> 16) & 1u)) >> 16);  // RNE
}
HD float lo16(unsigned int u) { return __uint_as_float(u << 16); }
HD float hi16(unsigned int u) { return __uint_as_float(u & 0xffff0000u); }
HD float bf2f(unsigned short u) { return __uint_as_float(((unsigned int)u) << 16); }

// gelu tanh-approx via sigmoid identity: 0.5(1+tanh(z)) == sigmoid(2z).
HD float gelu_f(float x) {
    float u = x * (-1.5957691216057308f - 0.07135481627f * (x * x));
    return x * __builtin_amdgcn_rcpf(1.f + __expf(u));
}

// ---------------------------------------------------------------------------
// All 8 weight repacks in one dispatch.
// ---------------------------------------------------------------------------
__global__ void repack_all(const float* __restrict__ Wff1,
                           const float* __restrict__ Wmp1,
                           const float* __restrict__ Wmp2,
                           const float* __restrict__ Wff2,
                           unsigned short* __restrict__ Bp) {
    const int begs[9] = {0, 65536, 131072, 196608, 212992, 278528, 344064,
                         360448, 425984};
    const int srcid[8] = {0, 1, 1, 1, 2, 2, 2, 3};
    const int rowoff[8] = {0, 0, 256, 512, 0, 256, 512, 0};
    int i = blockIdx.x * 256 + threadIdx.x;
    if (i >= 425984) return;
    int s = 0;
#pragma unroll
    for (int k = 1; k < 8; ++k)
        if (i >= begs[k]) s = k;
    const float* Ws[4] = {Wff1, Wmp1, Wmp2, Wff2};
    const float* B = Ws[srcid[s]];
    int local = i - begs[s];
    int k = local >> 8, n = local & 255;
    int kb = k >> 5, kr = k & 31;
    int quad = kr >> 3, j = kr & 7;
    int lane = quad * 16 + (n & 15);
    int nt = n >> 4;
    Bp[begs[s] + ((((kb * 16 + nt) * 64) + lane) << 3) + j] =
        f2bf(B[(size_t)(rowoff[s] + k) * 256 + n]);
}

// ---------------------------------------------------------------------------
// General LDS-free bf16 MFMA GEMM (64x64 tile, grid (ceil(M/64),4)) for FFNs.
// ---------------------------------------------------------------------------
__global__ __launch_bounds__(256) void gemm_kernel(
    const void* __restrict__ Av, int a_is_f32, int M, int K,
    const unsigned short* __restrict__ Bp,
    const float* __restrict__ bias, const float* __restrict__ resid,
    unsigned short* __restrict__ Cb, float* __restrict__ Cf, int do_gelu) {
    int lane = threadIdx.x & 63;
    int w = threadIdx.x >> 6;
    int row0 = blockIdx.x * 64 + w * 16;
    int n0 = blockIdx.y * 64;
    int m15 = lane & 15, quad = lane >> 4;

    int arow = row0 + m15;
    if (arow > M - 1) arow = M - 1;

    f32x4 acc[4] = {{0,0,0,0},{0,0,0,0},{0,0,0,0},{0,0,0,0}};
    const float* Af = (const float*)Av + (size_t)arow * K + quad * 8;
    const unsigned short* Ab = (const unsigned short*)Av + (size_t)arow * K + quad * 8;

    for (int kt = 0; kt < K; kt += 32) {
        short8 a;
        if (a_is_f32) {
            f32x4 lo = *(const f32x4*)(Af + kt);
            f32x4 hi = *(const f32x4*)(Af + kt + 4);
#pragma unroll
            for (int j = 0; j < 4; ++j) {
                a[j] = (short)f2bf(lo[j]);
                a[j + 4] = (short)f2bf(hi[j]);
            }
        } else {
            a = *(const short8*)(Ab + kt);
        }
        const unsigned short* bbase =
            Bp + ((((size_t)(kt >> 5) * 16 + (n0 >> 4)) * 64 + lane) << 3);
#pragma unroll
        for (int nt = 0; nt < 4; ++nt) {
            short8 b = *(const short8*)(bbase + nt * 64 * 8);
            acc[nt] = __builtin_amdgcn_mfma_f32_16x16x32_bf16(a, b, acc[nt], 0, 0, 0);
        }
    }

#pragma unroll
    for (int nt = 0; nt < 4; ++nt) {
        int col = n0 + nt * 16 + m15;
        float bv = bias ? bias[col] : 0.f;
#pragma unroll
        for (int r = 0; r < 4; ++r) {
            int row = row0 + quad * 4 + r;
            if (row < M) {
                float v = acc[nt][r] + bv;
                if (do_gelu) v = gelu_f(v);
                size_t idx = (size_t)row * 256 + col;
                if (resid) v += resid[idx];
                if (Cb) Cb[idx] = f2bf(v);
                if (Cf) Cf[idx] = v;
            }
        }
    }
}

// ---------------------------------------------------------------------------
// P and Q in one dispatch: grid ((M+63)/64, 8); y<4 -> P cols, y>=4 -> Q cols.
// ---------------------------------------------------------------------------
__global__ __launch_bounds__(256) void pq_kernel(
    const unsigned short* __restrict__ A, int M,
    const unsigned short* __restrict__ BpA, const unsigned short* __restrict__ BpB,
    const float* __restrict__ qbias,
    unsigned short* __restrict__ Pb, unsigned short* __restrict__ Qb) {
    int lane = threadIdx.x & 63;
    int w = threadIdx.x >> 6;
    int row0 = blockIdx.x * 64 + w * 16;
    int isQ = blockIdx.y >> 2;
    int n0 = (blockIdx.y & 3) * 64;
    const unsigned short* Bp = isQ ? BpB : BpA;
    unsigned short* out = isQ ? Qb : Pb;
    int m15 = lane & 15, quad = lane >> 4;

    int arow = row0 + m15;
    if (arow > M - 1) arow = M - 1;
    const unsigned short* Ab = A + (size_t)arow * 256 + quad * 8;

    f32x4 acc[4] = {{0,0,0,0},{0,0,0,0},{0,0,0,0},{0,0,0,0}};
    for (int kt = 0; kt < 256; kt += 32) {
        short8 a = *(const short8*)(Ab + kt);
        const unsigned short* bbase =
            Bp + ((((size_t)(kt >> 5) * 16 + (n0 >> 4)) * 64 + lane) << 3);
#pragma unroll
        for (int nt = 0; nt < 4; ++nt) {
            short8 b = *(const short8*)(bbase + nt * 64 * 8);
            acc[nt] = __builtin_amdgcn_mfma_f32_16x16x32_bf16(a, b, acc[nt], 0, 0, 0);
        }
    }

#pragma unroll
    for (int nt = 0; nt < 4; ++nt) {
        int col = n0 + nt * 16 + m15;
        float bv = isQ ? qbias[col] : 0.f;
#pragma unroll
        for (int r = 0; r < 4; ++r) {
            int row = row0 + quad * 4 + r;
            if (row < M) out[(size_t)row * 256 + col] = f2bf(acc[nt][r] + bv);
        }
    }
}

// ---------------------------------------------------------------------------
// Counting sort by dst: zero -> histogram -> single-block scan -> scatter.
// ---------------------------------------------------------------------------
__global__ void zero_i32(int* __restrict__ p, int n) {
    int i = blockIdx.x * 256 + threadIdx.x;
    if (i < n) p[i] = 0;
}
__global__ void hist_kernel(const int* __restrict__ dst, int* __restrict__ cnt, int E) {
    int e = blockIdx.x * 256 + threadIdx.x;
    if (e < E) atomicAdd(&cnt[dst[e]], 1);
}
__global__ __launch_bounds__(1024) void scan_kernel(const int* __restrict__ cnt,
                                                    int* __restrict__ cursor, int N) {
    __shared__ int part[1024];
    int tid = threadIdx.x;
    int per = (N + 1023) / 1024;
    int lo = tid * per;
    int s = 0;
    for (int j = 0; j < per; ++j) {
        int idx = lo + j;
        if (idx < N) s += cnt[idx];
    }
    part[tid] = s;
    __syncthreads();
    for (int off = 1; off < 1024; off <<= 1) {
        int t = (tid >= off) ? part[tid - off] : 0;
        __syncthreads();
        part[tid] += t;
        __syncthreads();
    }
    int run = (tid > 0) ? part[tid - 1] : 0;
    for (int j = 0; j < per; ++j) {
        int idx = lo + j;
        if (idx < N) {
            cursor[idx] = run;
            run += cnt[idx];
        }
    }
}
__global__ void scatter_kernel(const int* __restrict__ src, const int* __restrict__ dst,
                               int* __restrict__ cursor, int* __restrict__ perm,
                               int* __restrict__ srcs, int* __restrict__ dsts, int E) {
    int e = blockIdx.x * 256 + threadIdx.x;
    if (e < E) {
        int d = dst[e];
        int pos = atomicAdd(&cursor[d], 1);
        perm[pos] = e;
        srcs[pos] = src[e];
        dsts[pos] = d;
    }
}

// ---------------------------------------------------------------------------
// FUSED edge kernel. Block = 64 sorted edges (grid ceil(E/64), 256 thr).
// Phase 1: R[64x256] = bf16(ef[perm[e]] @ Wc) -> LDS tile (MFMA).
// Phase 2: wave w owns channel slice [w*64, w*64+64), 1 ch/lane; walks all
// 64 edges with 8-deep batched P (global) + R (LDS) loads. Interior segments
// plain-RMW Hacc (channel-disjoint waves => no race); boundary segments
// (<=2/block) atomicAdd.
// ---------------------------------------------------------------------------
__global__ __launch_bounds__(256) void fused_kernel(
    const float* __restrict__ ef, const int* __restrict__ perm,
    const int* __restrict__ srcs, const int* __restrict__ dsts,
    const unsigned short* __restrict__ BpC,
    const unsigned short* __restrict__ Pb, const unsigned short* __restrict__ Qb,
    const int* __restrict__ cursor, const int* __restrict__ cnt,
    float* __restrict__ Hacc, int E) {
    __shared__ unsigned short tile[64 * 256];  // 32 KB, R tile bf16
    int lane = threadIdx.x & 63;
    int w = threadIdx.x >> 6;
    int e_lo = blockIdx.x * 64;
    int n_e = E - e_lo;
    if (n_e > 64) n_e = 64;
    int e_hi = e_lo + n_e;

    // per-lane src/dst of the block's 64 edges (broadcast via readlane later)
    int eidx = e_lo + lane;
    if (eidx > E - 1) eidx = E - 1;
    int vs = srcs[eidx];
    int vd = dsts[eidx];

    // ---- Phase 1: MFMA R tile (identical math to old rgemm_kernel) ----
    int m15 = lane & 15, quad = lane >> 4;
    int arow = e_lo + w * 16 + m15;
    if (arow > E - 1) arow = E - 1;
    int grow = perm[arow];
    const float* Af = ef + (size_t)grow * 64 + quad * 8;

    f32x4 acc[16];
#pragma unroll
    for (int i = 0; i < 16; ++i) acc[i] = {0.f, 0.f, 0.f, 0.f};

#pragma unroll
    for (int kb = 0; kb < 2; ++kb) {
        f32x4 lo = *(const f32x4*)(Af + kb * 32);
        f32x4 hi = *(const f32x4*)(Af + kb * 32 + 4);
        short8 a;
#pragma unroll
        for (int j = 0; j < 4; ++j) {
            a[j] = (short)f2bf(lo[j]);
            a[j + 4] = (short)f2bf(hi[j]);
        }
        const unsigned short* bb = BpC + (((size_t)kb * 16 * 64 + lane) << 3);
#pragma unroll
        for (int nt = 0; nt < 16; ++nt) {
            short8 b = *(const short8*)(bb + (size_t)nt * 64 * 8);
            acc[nt] = __builtin_amdgcn_mfma_f32_16x16x32_bf16(a, b, acc[nt], 0, 0, 0);
        }
    }

#pragma unroll
    for (int nt = 0; nt < 16; ++nt) {
        int col = nt * 16 + m15;
#pragma unroll
        for (int r = 0; r < 4; ++r) {
            int lrow = w * 16 + quad * 4 + r;
            tile[lrow * 256 + col] = f2bf(acc[nt][r]);
        }
    }
    __syncthreads();

    // ---- Phase 2: channel-sliced walk of all 64 edges ----
    int c = threadIdx.x;  // channel; wave w covers [w*64, w*64+64)
    float a = 0.f;
    int cur_d = __builtin_amdgcn_readlane(vd, 0);
    float qv = bf2f(Qb[(((size_t)cur_d) << 8) + c]);
    int end_c = cursor[cur_d];
    int beg_c = end_c - cnt[cur_d];

#pragma unroll
    for (int k0 = 0; k0 < 64; k0 += 8) {
        // batch: 8 independent P gathers (128B/wave each) + 8 LDS R reads
        float pv[8], rv[8];
#pragma unroll
        for (int j = 0; j < 8; ++j) {
            int s = __builtin_amdgcn_readlane(vs, k0 + j);
            pv[j] = bf2f(Pb[(((size_t)s) << 8) + c]);
            rv[j] = bf2f(tile[((k0 + j) << 8) + c]);
        }
#pragma unroll
        for (int j = 0; j < 8; ++j) {
            if (k0 + j < n_e) {
                int d = __builtin_amdgcn_readlane(vd, k0 + j);
                if (d != cur_d) {
                    size_t hidx = (((size_t)cur_d) << 8) + c;
                    if (beg_c >= e_lo && end_c <= e_hi)
                        Hacc[hidx] += a;           // interior: this block only
                    else
                        atomicAdd(&Hacc[hidx], a); // boundary segment
                    a = 0.f;
                    cur_d = d;
                    qv = bf2f(Qb[(((size_t)d) << 8) + c]);
                    end_c = cursor[d];
                    beg_c = end_c - cnt[d];
                }
                a += gelu_f(pv[j] + qv + rv[j]);
            }
        }
    }
    {
        size_t hidx = (((size_t)cur_d) << 8) + c;
        if (beg_c >= e_lo && end_c <= e_hi)
            Hacc[hidx] += a;
        else
            atomicAdd(&Hacc[hidx], a);
    }
}

// ---------------------------------------------------------------------------
// h_bf = bf16(Hacc), vectorized (float4 -> uint2). n4 = N*256/4.
// ---------------------------------------------------------------------------
__global__ void finalize_h(const float* __restrict__ Hacc,
                           unsigned short* __restrict__ h_bf, int n4) {
    int i = blockIdx.x * 256 + threadIdx.x;
    if (i < n4) {
        float4 v = ((const float4*)Hacc)[i];
        uint2 o;
        o.x = (unsigned int)f2bf(v.x) | ((unsigned int)f2bf(v.y) << 16);
        o.y = (unsigned int)f2bf(v.z) | ((unsigned int)f2bf(v.w) << 16);
        ((uint2*)h_bf)[i] = o;
    }
}

// ---------------------------------------------------------------------------
extern "C" void kernel_launch(void* const* d_in, const int* in_sizes, int n_in,
                              void* d_out, int out_size, void* d_ws, size_t ws_size,
                              hipStream_t stream) {
    const float* x     = (const float*)d_in[0];
    const int*   ei    = (const int*)d_in[1];
    const float* ef    = (const float*)d_in[2];
    const float* W_ff1 = (const float*)d_in[3];
    const float* b_ff1 = (const float*)d_in[4];
    const float* W_mp1 = (const float*)d_in[5];
    const float* b_mp1 = (const float*)d_in[6];
    const float* W_mp2 = (const float*)d_in[7];
    const float* b_mp2 = (const float*)d_in[8];
    const float* W_ff2 = (const float*)d_in[9];
    const float* b_ff2 = (const float*)d_in[10];

    const int N = in_sizes[0] / 256;  // 10000
    const int E = in_sizes[1] / 2;    // 320000
    const int* src = ei;
    const int* dst = ei + E;

    // ---- workspace carve (256B-aligned bumps) ----
    char* p = (char*)d_ws;
    unsigned short* h_bf = (unsigned short*)p;  p += ((size_t)N * 256 * 2 + 255) & ~255ull;
    unsigned short* Pbuf = (unsigned short*)p;  p += ((size_t)N * 256 * 2 + 255) & ~255ull;
    unsigned short* Qbuf = (unsigned short*)p;  p += ((size_t)N * 256 * 2 + 255) & ~255ull;
    float* Hacc = (float*)p;                    p += ((size_t)N * 256 * 4 + 255) & ~255ull;
    unsigned short* Bp = (unsigned short*)p;    p += (425984ull * 2 + 255) & ~255ull;
    int* cnt    = (int*)p;                      p += ((size_t)N * 4 + 255) & ~255ull;
    int* cursor = (int*)p;                      p += ((size_t)N * 4 + 255) & ~255ull;
    int* perm   = (int*)p;                      p += ((size_t)E * 4 + 255) & ~255ull;
    int* srcs   = (int*)p;                      p += ((size_t)E * 4 + 255) & ~255ull;
    int* dsts   = (int*)p;                      p += ((size_t)E * 4 + 255) & ~255ull;

    unsigned short* Bp_ff1 = Bp + 0;
    unsigned short* Bp_a1  = Bp + 65536;
    unsigned short* Bp_b1  = Bp + 131072;
    unsigned short* Bp_c1  = Bp + 196608;
    unsigned short* Bp_a2  = Bp + 212992;
    unsigned short* Bp_b2  = Bp + 278528;
    unsigned short* Bp_c2  = Bp + 344064;
    unsigned short* Bp_ff2 = Bp + 360448;

    // ---- repack all weights (single dispatch) ----
    repack_all<<<1664, 256, 0, stream>>>(W_ff1, W_mp1, W_mp2, W_ff2, Bp);

    // ---- counting sort of edges by dst (CSR) ----
    zero_i32<<<(N + 255) / 256, 256, 0, stream>>>(cnt, N);
    hist_kernel<<<(E + 255) / 256, 256, 0, stream>>>(dst, cnt, E);
    scan_kernel<<<1, 1024, 0, stream>>>(cnt, cursor, N);
    scatter_kernel<<<(E + 255) / 256, 256, 0, stream>>>(src, dst, cursor, perm, srcs,
                                                        dsts, E);

    dim3 gN((N + 63) / 64, 4);
    dim3 gPQ((N + 63) / 64, 8);

    // ---- FFN1: h = gelu(x@W_ff1 + b); h_bf for GEMMs, Hacc = f32 accumulator
    gemm_kernel<<<gN, 256, 0, stream>>>(x, 1, N, 256, Bp_ff1, b_ff1, nullptr,
                                        h_bf, Hacc, 1);

    const unsigned short* Bp_a[2] = {Bp_a1, Bp_a2};
    const unsigned short* Bp_b[2] = {Bp_b1, Bp_b2};
    const unsigned short* Bp_c[2] = {Bp_c1, Bp_c2};
    const float* bmp[2] = {b_mp1, b_mp2};

    for (int l = 0; l < 2; ++l) {
        pq_kernel<<<gPQ, 256, 0, stream>>>(h_bf, N, Bp_a[l], Bp_b[l], bmp[l],
                                           Pbuf, Qbuf);
        fused_kernel<<<(E + 63) / 64, 256, 0, stream>>>(
            ef, perm, srcs, dsts, Bp_c[l], Pbuf, Qbuf, cursor, cnt, Hacc, E);
        if (l == 0)
            finalize_h<<<(N * 64 + 255) / 256, 256, 0, stream>>>(Hacc, h_bf, N * 64);
    }

    // ---- FFN2: out = x + bf16(Hacc)@W_ff2 + b  (reads Hacc directly) ----
    gemm_kernel<<<gN, 256, 0, stream>>>(Hacc, 1, N, 256, Bp_ff2, b_ff2, x,
                                        nullptr, (float*)d_out, 0);
}

// Round 5
// 471.421 us; speedup vs baseline: 1.2855x; 1.0994x over previous
//
#include <hip/hip_runtime.h>

// ---------------------------------------------------------------------------
// ResBlock GNN layer on MI355X (gfx950). ALL tensors fp32.
//   h  = gelu(x @ W_ff1 + b)
//   h += seg_sum(gelu(P[src]+Q[dst]+R_e+b_mp)), P=h@Wa, Q=h@Wb, R=ef@Wc  (x2)
//   out = x + h @ W_ff2 + b
// R11: fused edge kernel, occupancy + pipeline + LDS-swizzle rework.
//  - Block = 128 threads (2 waves) = one 64-edge tile x one 128-channel half.
//    LDS 16 KB -> ~10 blocks/CU (was 32 KB -> 2.5 resident, 31% occupancy).
//  - Phase 2: explicit double-buffered prefetch (LOADB(t+1) before CONS(t),
//    static pvA/pvB regs) -> 16 loads in flight across segment logic.
//  - LDS tile XOR-swizzled (col ^= quad<<4 on store, inverse on read with
//    compile-time k) -> conflict-free both sides (was 2.56M conflicts).
//  - Full-tile fast path has zero per-edge bounds branches (E % 64 == 0).
// Interior segments plain-RMW Hacc (channel-disjoint waves/blocks); boundary
// segments atomicAdd. R tile LDS-only via MFMA.
// ---------------------------------------------------------------------------

typedef __attribute__((ext_vector_type(8))) short short8;
typedef __attribute__((ext_vector_type(4))) float f32x4;

#define HD __device__ __forceinline__

HD unsigned short f2bf(float f) {
    unsigned int u = __float_as_uint(f);
    return (unsigned short)((u + 0x7fffu + ((u >> 16) & 1u)) >> 16);  // RNE
}
HD float lo16(unsigned int u) { return __uint_as_float(u << 16); }
HD float hi16(unsigned int u) { return __uint_as_float(u & 0xffff0000u); }
HD float bf2f(unsigned short u) { return __uint_as_float(((unsigned int)u) << 16); }

// gelu tanh-approx via sigmoid identity: 0.5(1+tanh(z)) == sigmoid(2z).
HD float gelu_f(float x) {
    float u = x * (-1.5957691216057308f - 0.07135481627f * (x * x));
    return x * __builtin_amdgcn_rcpf(1.f + __expf(u));
}

// ---------------------------------------------------------------------------
// All 8 weight repacks in one dispatch.
// ---------------------------------------------------------------------------
__global__ void repack_all(const float* __restrict__ Wff1,
                           const float* __restrict__ Wmp1,
                           const float* __restrict__ Wmp2,
                           const float* __restrict__ Wff2,
                           unsigned short* __restrict__ Bp) {
    const int begs[9] = {0, 65536, 131072, 196608, 212992, 278528, 344064,
                         360448, 425984};
    const int srcid[8] = {0, 1, 1, 1, 2, 2, 2, 3};
    const int rowoff[8] = {0, 0, 256, 512, 0, 256, 512, 0};
    int i = blockIdx.x * 256 + threadIdx.x;
    if (i >= 425984) return;
    int s = 0;
#pragma unroll
    for (int k = 1; k < 8; ++k)
        if (i >= begs[k]) s = k;
    const float* Ws[4] = {Wff1, Wmp1, Wmp2, Wff2};
    const float* B = Ws[srcid[s]];
    int local = i - begs[s];
    int k = local >> 8, n = local & 255;
    int kb = k >> 5, kr = k & 31;
    int quad = kr >> 3, j = kr & 7;
    int lane = quad * 16 + (n & 15);
    int nt = n >> 4;
    Bp[begs[s] + ((((kb * 16 + nt) * 64) + lane) << 3) + j] =
        f2bf(B[(size_t)(rowoff[s] + k) * 256 + n]);
}

// ---------------------------------------------------------------------------
// General LDS-free bf16 MFMA GEMM (64x64 tile, grid (ceil(M/64),4)) for FFNs.
// ---------------------------------------------------------------------------
__global__ __launch_bounds__(256) void gemm_kernel(
    const void* __restrict__ Av, int a_is_f32, int M, int K,
    const unsigned short* __restrict__ Bp,
    const float* __restrict__ bias, const float* __restrict__ resid,
    unsigned short* __restrict__ Cb, float* __restrict__ Cf, int do_gelu) {
    int lane = threadIdx.x & 63;
    int w = threadIdx.x >> 6;
    int row0 = blockIdx.x * 64 + w * 16;
    int n0 = blockIdx.y * 64;
    int m15 = lane & 15, quad = lane >> 4;

    int arow = row0 + m15;
    if (arow > M - 1) arow = M - 1;

    f32x4 acc[4] = {{0,0,0,0},{0,0,0,0},{0,0,0,0},{0,0,0,0}};
    const float* Af = (const float*)Av + (size_t)arow * K + quad * 8;
    const unsigned short* Ab = (const unsigned short*)Av + (size_t)arow * K + quad * 8;

    for (int kt = 0; kt < K; kt += 32) {
        short8 a;
        if (a_is_f32) {
            f32x4 lo = *(const f32x4*)(Af + kt);
            f32x4 hi = *(const f32x4*)(Af + kt + 4);
#pragma unroll
            for (int j = 0; j < 4; ++j) {
                a[j] = (short)f2bf(lo[j]);
                a[j + 4] = (short)f2bf(hi[j]);
            }
        } else {
            a = *(const short8*)(Ab + kt);
        }
        const unsigned short* bbase =
            Bp + ((((size_t)(kt >> 5) * 16 + (n0 >> 4)) * 64 + lane) << 3);
#pragma unroll
        for (int nt = 0; nt < 4; ++nt) {
            short8 b = *(const short8*)(bbase + nt * 64 * 8);
            acc[nt] = __builtin_amdgcn_mfma_f32_16x16x32_bf16(a, b, acc[nt], 0, 0, 0);
        }
    }

#pragma unroll
    for (int nt = 0; nt < 4; ++nt) {
        int col = n0 + nt * 16 + m15;
        float bv = bias ? bias[col] : 0.f;
#pragma unroll
        for (int r = 0; r < 4; ++r) {
            int row = row0 + quad * 4 + r;
            if (row < M) {
                float v = acc[nt][r] + bv;
                if (do_gelu) v = gelu_f(v);
                size_t idx = (size_t)row * 256 + col;
                if (resid) v += resid[idx];
                if (Cb) Cb[idx] = f2bf(v);
                if (Cf) Cf[idx] = v;
            }
        }
    }
}

// ---------------------------------------------------------------------------
// P and Q in one dispatch: grid ((M+63)/64, 8); y<4 -> P cols, y>=4 -> Q cols.
// ---------------------------------------------------------------------------
__global__ __launch_bounds__(256) void pq_kernel(
    const unsigned short* __restrict__ A, int M,
    const unsigned short* __restrict__ BpA, const unsigned short* __restrict__ BpB,
    const float* __restrict__ qbias,
    unsigned short* __restrict__ Pb, unsigned short* __restrict__ Qb) {
    int lane = threadIdx.x & 63;
    int w = threadIdx.x >> 6;
    int row0 = blockIdx.x * 64 + w * 16;
    int isQ = blockIdx.y >> 2;
    int n0 = (blockIdx.y & 3) * 64;
    const unsigned short* Bp = isQ ? BpB : BpA;
    unsigned short* out = isQ ? Qb : Pb;
    int m15 = lane & 15, quad = lane >> 4;

    int arow = row0 + m15;
    if (arow > M - 1) arow = M - 1;
    const unsigned short* Ab = A + (size_t)arow * 256 + quad * 8;

    f32x4 acc[4] = {{0,0,0,0},{0,0,0,0},{0,0,0,0},{0,0,0,0}};
    for (int kt = 0; kt < 256; kt += 32) {
        short8 a = *(const short8*)(Ab + kt);
        const unsigned short* bbase =
            Bp + ((((size_t)(kt >> 5) * 16 + (n0 >> 4)) * 64 + lane) << 3);
#pragma unroll
        for (int nt = 0; nt < 4; ++nt) {
            short8 b = *(const short8*)(bbase + nt * 64 * 8);
            acc[nt] = __builtin_amdgcn_mfma_f32_16x16x32_bf16(a, b, acc[nt], 0, 0, 0);
        }
    }

#pragma unroll
    for (int nt = 0; nt < 4; ++nt) {
        int col = n0 + nt * 16 + m15;
        float bv = isQ ? qbias[col] : 0.f;
#pragma unroll
        for (int r = 0; r < 4; ++r) {
            int row = row0 + quad * 4 + r;
            if (row < M) out[(size_t)row * 256 + col] = f2bf(acc[nt][r] + bv);
        }
    }
}

// ---------------------------------------------------------------------------
// Counting sort by dst: zero -> histogram -> single-block scan -> scatter.
// ---------------------------------------------------------------------------
__global__ void zero_i32(int* __restrict__ p, int n) {
    int i = blockIdx.x * 256 + threadIdx.x;
    if (i < n) p[i] = 0;
}
__global__ void hist_kernel(const int* __restrict__ dst, int* __restrict__ cnt, int E) {
    int e = blockIdx.x * 256 + threadIdx.x;
    if (e < E) atomicAdd(&cnt[dst[e]], 1);
}
__global__ __launch_bounds__(1024) void scan_kernel(const int* __restrict__ cnt,
                                                    int* __restrict__ cursor, int N) {
    __shared__ int part[1024];
    int tid = threadIdx.x;
    int per = (N + 1023) / 1024;
    int lo = tid * per;
    int s = 0;
    for (int j = 0; j < per; ++j) {
        int idx = lo + j;
        if (idx < N) s += cnt[idx];
    }
    part[tid] = s;
    __syncthreads();
    for (int off = 1; off < 1024; off <<= 1) {
        int t = (tid >= off) ? part[tid - off] : 0;
        __syncthreads();
        part[tid] += t;
        __syncthreads();
    }
    int run = (tid > 0) ? part[tid - 1] : 0;
    for (int j = 0; j < per; ++j) {
        int idx = lo + j;
        if (idx < N) {
            cursor[idx] = run;
            run += cnt[idx];
        }
    }
}
__global__ void scatter_kernel(const int* __restrict__ src, const int* __restrict__ dst,
                               int* __restrict__ cursor, int* __restrict__ perm,
                               int* __restrict__ srcs, int* __restrict__ dsts, int E) {
    int e = blockIdx.x * 256 + threadIdx.x;
    if (e < E) {
        int d = dst[e];
        int pos = atomicAdd(&cursor[d], 1);
        perm[pos] = e;
        srcs[pos] = src[e];
        dsts[pos] = d;
    }
}

// ---------------------------------------------------------------------------
// FUSED edge kernel. Block = 128 threads (2 waves) = 64-edge tile x 128-ch
// half. grid = 2*ceil(E/64); tile_id = bid>>1, half = bid&1.
// Phase 1: R[64 x 128ch] = bf16(ef[perm[e]] @ Wc[:, half]) -> LDS (MFMA),
//   XOR-swizzled: store col' = col ^ (quad<<4) -> conflict-free store+read.
// Phase 2: c = half*128 + tid; both waves walk all 64 edges with explicit
//   double-buffered prefetch (LOADB(t+1) before CONS(t)). Interior segments
//   plain-RMW Hacc; boundary segments atomicAdd.
// ---------------------------------------------------------------------------
#define LOADB(pv, rv, T0)                                                     \
    _Pragma("unroll") for (int j = 0; j < 8; ++j) {                           \
        int s = __builtin_amdgcn_readlane(vs, (T0) * 8 + j);                  \
        pv[j] = bf2f(Pb[((size_t)s << 8) + c]);                               \
        rv[j] = bf2f(tile[((T0) * 8 + j) * 128 +                              \
                          (c_local ^ (((((T0) * 8 + j) >> 2) & 3) << 4))]);   \
    }

#define CONS(pv, rv, T0)                                                      \
    _Pragma("unroll") for (int j = 0; j < 8; ++j) {                           \
        int k = (T0) * 8 + j;                                                 \
        if (k > 0) {                                                          \
            int d = __builtin_amdgcn_readlane(vd, k);                         \
            if (d != cur_d) {                                                 \
                size_t hidx = ((size_t)cur_d << 8) + c;                       \
                if (beg_c >= e_lo && end_c <= e_hi)                           \
                    Hacc[hidx] += a;                                          \
                else                                                          \
                    atomicAdd(&Hacc[hidx], a);                                \
                a = 0.f;                                                      \
                cur_d = d;                                                    \
                qv = bf2f(Qb[((size_t)d << 8) + c]);                          \
                end_c = cursor[d];                                            \
                beg_c = end_c - cnt[d];                                       \
            }                                                                 \
        }                                                                     \
        a += gelu_f(pv[j] + qv + rv[j]);                                      \
    }

__global__ __launch_bounds__(128) void fused_kernel(
    const float* __restrict__ ef, const int* __restrict__ perm,
    const int* __restrict__ srcs, const int* __restrict__ dsts,
    const unsigned short* __restrict__ BpC,
    const unsigned short* __restrict__ Pb, const unsigned short* __restrict__ Qb,
    const int* __restrict__ cursor, const int* __restrict__ cnt,
    float* __restrict__ Hacc, int E) {
    __shared__ unsigned short tile[64 * 128];  // 16 KB, swizzled R half-tile
    int lane = threadIdx.x & 63;
    int w = threadIdx.x >> 6;  // 0..1
    int tile_id = blockIdx.x >> 1;
    int half = blockIdx.x & 1;
    int e_lo = tile_id * 64;
    int n_e = E - e_lo;
    if (n_e > 64) n_e = 64;
    int e_hi = e_lo + n_e;

    // per-lane src/dst of the tile's 64 edges (broadcast via readlane later)
    int eidx = e_lo + lane;
    if (eidx > E - 1) eidx = E - 1;
    int vs = srcs[eidx];
    int vd = dsts[eidx];

    int m15 = lane & 15, quad = lane >> 4;

    // ---- Phase 1: MFMA R half-tile. Wave w: rows w*32 + rt*16. ----
    int ar0 = e_lo + w * 32 + m15;
    int ar1 = ar0 + 16;
    if (ar0 > E - 1) ar0 = E - 1;
    if (ar1 > E - 1) ar1 = E - 1;
    int g0 = perm[ar0], g1 = perm[ar1];
    const float* A0 = ef + (size_t)g0 * 64 + quad * 8;
    const float* A1 = ef + (size_t)g1 * 64 + quad * 8;

    f32x4 acc[2][8];
#pragma unroll
    for (int rt = 0; rt < 2; ++rt)
#pragma unroll
        for (int nt = 0; nt < 8; ++nt) acc[rt][nt] = {0.f, 0.f, 0.f, 0.f};

#pragma unroll
    for (int kb = 0; kb < 2; ++kb) {
        f32x4 lo0 = *(const f32x4*)(A0 + kb * 32);
        f32x4 hi0 = *(const f32x4*)(A0 + kb * 32 + 4);
        f32x4 lo1 = *(const f32x4*)(A1 + kb * 32);
        f32x4 hi1 = *(const f32x4*)(A1 + kb * 32 + 4);
        short8 a0, a1;
#pragma unroll
        for (int j = 0; j < 4; ++j) {
            a0[j] = (short)f2bf(lo0[j]);
            a0[j + 4] = (short)f2bf(hi0[j]);
            a1[j] = (short)f2bf(lo1[j]);
            a1[j + 4] = (short)f2bf(hi1[j]);
        }
#pragma unroll
        for (int nt = 0; nt < 8; ++nt) {
            short8 b = *(const short8*)(
                BpC + (((size_t)(kb * 16 + half * 8 + nt) * 64 + lane) << 3));
            acc[0][nt] = __builtin_amdgcn_mfma_f32_16x16x32_bf16(a0, b, acc[0][nt], 0, 0, 0);
            acc[1][nt] = __builtin_amdgcn_mfma_f32_16x16x32_bf16(a1, b, acc[1][nt], 0, 0, 0);
        }
    }

    // swizzled store: col' = (nt^quad)*16 + m15  (channel nt*16+m15)
#pragma unroll
    for (int rt = 0; rt < 2; ++rt)
#pragma unroll
        for (int nt = 0; nt < 8; ++nt) {
            int colp = ((nt ^ quad) << 4) + m15;
#pragma unroll
            for (int r = 0; r < 4; ++r) {
                int row = w * 32 + rt * 16 + quad * 4 + r;
                tile[row * 128 + colp] = f2bf(acc[rt][nt][r]);
            }
        }
    __syncthreads();

    // ---- Phase 2: both waves walk all 64 edges; c = half*128 + tid ----
    int c_local = threadIdx.x;          // 0..127
    int c = (half << 7) + c_local;      // global channel

    int cur_d = __builtin_amdgcn_readlane(vd, 0);
    float qv = bf2f(Qb[((size_t)cur_d << 8) + c]);
    int end_c = cursor[cur_d];
    int beg_c = end_c - cnt[cur_d];
    float a = 0.f;

    if (n_e == 64) {
        float pvA[8], rvA[8], pvB[8], rvB[8];
        LOADB(pvA, rvA, 0)
        LOADB(pvB, rvB, 1) CONS(pvA, rvA, 0)
        LOADB(pvA, rvA, 2) CONS(pvB, rvB, 1)
        LOADB(pvB, rvB, 3) CONS(pvA, rvA, 2)
        LOADB(pvA, rvA, 4) CONS(pvB, rvB, 3)
        LOADB(pvB, rvB, 5) CONS(pvA, rvA, 4)
        LOADB(pvA, rvA, 6) CONS(pvB, rvB, 5)
        LOADB(pvB, rvB, 7) CONS(pvA, rvA, 6)
        CONS(pvB, rvB, 7)
    } else {
        // tail tile (E % 64 != 0): simple guarded walk
        for (int k = 0; k < n_e; ++k) {
            int d = __builtin_amdgcn_readlane(vd, k);
            if (k > 0 && d != cur_d) {
                size_t hidx = ((size_t)cur_d << 8) + c;
                if (beg_c >= e_lo && end_c <= e_hi)
                    Hacc[hidx] += a;
                else
                    atomicAdd(&Hacc[hidx], a);
                a = 0.f;
                cur_d = d;
                qv = bf2f(Qb[((size_t)d << 8) + c]);
                end_c = cursor[d];
                beg_c = end_c - cnt[d];
            }
            int s = __builtin_amdgcn_readlane(vs, k);
            float pv = bf2f(Pb[((size_t)s << 8) + c]);
            float rv = bf2f(tile[k * 128 + (c_local ^ (((k >> 2) & 3) << 4))]);
            a += gelu_f(pv + qv + rv);
        }
    }
    {
        size_t hidx = ((size_t)cur_d << 8) + c;
        if (beg_c >= e_lo && end_c <= e_hi)
            Hacc[hidx] += a;
        else
            atomicAdd(&Hacc[hidx], a);
    }
}

// ---------------------------------------------------------------------------
// h_bf = bf16(Hacc), vectorized (float4 -> uint2). n4 = N*256/4.
// ---------------------------------------------------------------------------
__global__ void finalize_h(const float* __restrict__ Hacc,
                           unsigned short* __restrict__ h_bf, int n4) {
    int i = blockIdx.x * 256 + threadIdx.x;
    if (i < n4) {
        float4 v = ((const float4*)Hacc)[i];
        uint2 o;
        o.x = (unsigned int)f2bf(v.x) | ((unsigned int)f2bf(v.y) << 16);
        o.y = (unsigned int)f2bf(v.z) | ((unsigned int)f2bf(v.w) << 16);
        ((uint2*)h_bf)[i] = o;
    }
}

// ---------------------------------------------------------------------------
extern "C" void kernel_launch(void* const* d_in, const int* in_sizes, int n_in,
                              void* d_out, int out_size, void* d_ws, size_t ws_size,
                              hipStream_t stream) {
    const float* x     = (const float*)d_in[0];
    const int*   ei    = (const int*)d_in[1];
    const float* ef    = (const float*)d_in[2];
    const float* W_ff1 = (const float*)d_in[3];
    const float* b_ff1 = (const float*)d_in[4];
    const float* W_mp1 = (const float*)d_in[5];
    const float* b_mp1 = (const float*)d_in[6];
    const float* W_mp2 = (const float*)d_in[7];
    const float* b_mp2 = (const float*)d_in[8];
    const float* W_ff2 = (const float*)d_in[9];
    const float* b_ff2 = (const float*)d_in[10];

    const int N = in_sizes[0] / 256;  // 10000
    const int E = in_sizes[1] / 2;    // 320000
    const int* src = ei;
    const int* dst = ei + E;

    // ---- workspace carve (256B-aligned bumps) ----
    char* p = (char*)d_ws;
    unsigned short* h_bf = (unsigned short*)p;  p += ((size_t)N * 256 * 2 + 255) & ~255ull;
    unsigned short* Pbuf = (unsigned short*)p;  p += ((size_t)N * 256 * 2 + 255) & ~255ull;
    unsigned short* Qbuf = (unsigned short*)p;  p += ((size_t)N * 256 * 2 + 255) & ~255ull;
    float* Hacc = (float*)p;                    p += ((size_t)N * 256 * 4 + 255) & ~255ull;
    unsigned short* Bp = (unsigned short*)p;    p += (425984ull * 2 + 255) & ~255ull;
    int* cnt    = (int*)p;                      p += ((size_t)N * 4 + 255) & ~255ull;
    int* cursor = (int*)p;                      p += ((size_t)N * 4 + 255) & ~255ull;
    int* perm   = (int*)p;                      p += ((size_t)E * 4 + 255) & ~255ull;
    int* srcs   = (int*)p;                      p += ((size_t)E * 4 + 255) & ~255ull;
    int* dsts   = (int*)p;                      p += ((size_t)E * 4 + 255) & ~255ull;

    unsigned short* Bp_ff1 = Bp + 0;
    unsigned short* Bp_a1  = Bp + 65536;
    unsigned short* Bp_b1  = Bp + 131072;
    unsigned short* Bp_c1  = Bp + 196608;
    unsigned short* Bp_a2  = Bp + 212992;
    unsigned short* Bp_b2  = Bp + 278528;
    unsigned short* Bp_c2  = Bp + 344064;
    unsigned short* Bp_ff2 = Bp + 360448;

    // ---- repack all weights (single dispatch) ----
    repack_all<<<1664, 256, 0, stream>>>(W_ff1, W_mp1, W_mp2, W_ff2, Bp);

    // ---- counting sort of edges by dst (CSR) ----
    zero_i32<<<(N + 255) / 256, 256, 0, stream>>>(cnt, N);
    hist_kernel<<<(E + 255) / 256, 256, 0, stream>>>(dst, cnt, E);
    scan_kernel<<<1, 1024, 0, stream>>>(cnt, cursor, N);
    scatter_kernel<<<(E + 255) / 256, 256, 0, stream>>>(src, dst, cursor, perm, srcs,
                                                        dsts, E);

    dim3 gN((N + 63) / 64, 4);
    dim3 gPQ((N + 63) / 64, 8);
    int n_tiles = (E + 63) / 64;

    // ---- FFN1: h = gelu(x@W_ff1 + b); h_bf for GEMMs, Hacc = f32 accumulator
    gemm_kernel<<<gN, 256, 0, stream>>>(x, 1, N, 256, Bp_ff1, b_ff1, nullptr,
                                        h_bf, Hacc, 1);

    const unsigned short* Bp_a[2] = {Bp_a1, Bp_a2};
    const unsigned short* Bp_b[2] = {Bp_b1, Bp_b2};
    const unsigned short* Bp_c[2] = {Bp_c1, Bp_c2};
    const float* bmp[2] = {b_mp1, b_mp2};

    for (int l = 0; l < 2; ++l) {
        pq_kernel<<<gPQ, 256, 0, stream>>>(h_bf, N, Bp_a[l], Bp_b[l], bmp[l],
                                           Pbuf, Qbuf);
        fused_kernel<<<n_tiles * 2, 128, 0, stream>>>(
            ef, perm, srcs, dsts, Bp_c[l], Pbuf, Qbuf, cursor, cnt, Hacc, E);
        if (l == 0)
            finalize_h<<<(N * 64 + 255) / 256, 256, 0, stream>>>(Hacc, h_bf, N * 64);
    }

    // ---- FFN2: out = x + bf16(Hacc)@W_ff2 + b  (reads Hacc directly) ----
    gemm_kernel<<<gN, 256, 0, stream>>>(Hacc, 1, N, 256, Bp_ff2, b_ff2, x,
                                        nullptr, (float*)d_out, 0);
}